// Round 4
// baseline (209.964 us; speedup 1.0000x reference)
//
#include <hip/hip_runtime.h>

#define BATCH 131072
#define NS 64
#define NF 128
#define NTOT 192   // NS + NF
#define WPB 4      // waves (rays) per block

// wave64 inclusive add-scan via DPP: row_shr 1/2/4/8 (per-16 rows) then
// row_bcast:15 (rows 1,3) and row_bcast:31 (rows 2,3). Lane i = sum lanes 0..i;
// lane 63 = wave total. bound_ctrl=true => invalid source lanes contribute 0.
#define DPP_ADD_F(x, ctrl, rm)                                               \
    x += __int_as_float(__builtin_amdgcn_update_dpp(                         \
        0, __float_as_int(x), ctrl, rm, 0xf, true))
#define DPP_ADD_I(x, ctrl, rm)                                               \
    x += __builtin_amdgcn_update_dpp(0, x, ctrl, rm, 0xf, true)

__device__ __forceinline__ float wave_iscan_f(float x) {
    DPP_ADD_F(x, 0x111, 0xf);   // row_shr:1
    DPP_ADD_F(x, 0x112, 0xf);   // row_shr:2
    DPP_ADD_F(x, 0x114, 0xf);   // row_shr:4
    DPP_ADD_F(x, 0x118, 0xf);   // row_shr:8
    DPP_ADD_F(x, 0x142, 0xa);   // row_bcast:15 -> rows 1,3
    DPP_ADD_F(x, 0x143, 0xc);   // row_bcast:31 -> rows 2,3
    return x;
}
__device__ __forceinline__ int wave_iscan_i(int x) {
    DPP_ADD_I(x, 0x111, 0xf);
    DPP_ADD_I(x, 0x112, 0xf);
    DPP_ADD_I(x, 0x114, 0xf);
    DPP_ADD_I(x, 0x118, 0xf);
    DPP_ADD_I(x, 0x142, 0xa);
    DPP_ADD_I(x, 0x143, 0xc);
    return x;
}

__global__ __launch_bounds__(256) void pdf_sampler_kernel(
    const float* __restrict__ near_p,
    const float* __restrict__ far_p,
    const float* __restrict__ density,
    const float* __restrict__ rgb,
    float* __restrict__ out)
{
    const int lane = threadIdx.x & 63;
    const int wave = threadIdx.x >> 6;
    const int ray  = blockIdx.x * WPB + wave;

    __shared__ float2 s_cm[WPB][NS];          // (cdf, mid)
    __shared__ int2   s_hist2[WPB][NF / 2];   // histogram of t_j over k

    // All LDS traffic is wave-local: DS ops from one wave execute in order,
    // so wave_barrier() (compiler fence, 0 inst) replaces __syncthreads.
    const float nearv = near_p[ray];
    const float farv  = far_p[ray];
    const float dens  = density[ray * NS + lane];
    const float r = rgb[(ray * NS + lane) * 3 + 0];
    const float g = rgb[(ray * NS + lane) * 3 + 1];
    const float b = rgb[(ray * NS + lane) * 3 + 2];

    // zs_edges: near*(1-u) + far*u, u = i/64
    const float u0 = (float)lane       * (1.0f / 64.0f);
    const float u1 = (float)(lane + 1) * (1.0f / 64.0f);
    const float zs = nearv * (1.0f - u0) + farv * u0;
    const float ze = nearv * (1.0f - u1) + farv * u1;
    const float delta = ze - zs;
    const float mid   = 0.5f * (zs + ze);

    // Telescoped transmittance: one scan of density*delta does everything.
    const float S = wave_iscan_f(dens * delta);
    const float e = __expf(-S);
    // eprev = wave_shr:1, lane0 keeps old = 1.0f
    const float eprev = __int_as_float(__builtin_amdgcn_update_dpp(
        0x3f800000, __float_as_int(e), 0x138, 0xf, 0xf, false));
    const float w    = eprev - e;
    const float wsum = 1.0f - __shfl(e, 63, 64);
    const float cdfv = (1.0f - e) * __builtin_amdgcn_rcpf(wsum + 1e-6f);

    s_cm[wave][lane] = make_float2(cdfv, mid);
    s_hist2[wave][lane] = make_int2(0, 0);    // zero hist (k=2*lane, 2*lane+1)

    // t_j = first k in [0,128] with u_k >= cdf_j  (u_k = 0.05 + step*k).
    // ceilf guess is within +-1 of exact; two branchless corrections vs the
    // exact fmaf-evaluated predicate make it exact.
    const float step = 0.9f / 127.0f;
    int t = (int)ceilf((cdfv - 0.05f) * (127.0f / 0.9f));
    t = t < 0 ? 0 : (t > 128 ? 128 : t);
    t -= (t > 0   && __fmaf_rn(step, (float)(t - 1), 0.05f) >= cdfv) ? 1 : 0;
    t += (t < 128 && __fmaf_rn(step, (float)t,       0.05f) <  cdfv) ? 1 : 0;

    __builtin_amdgcn_wave_barrier();
    if (t < 128) atomicAdd(&((int*)s_hist2[wave])[t], 1);  // one balanced op
    __builtin_amdgcn_wave_barrier();

    // inds_k = #{j: t_j <= k} = cumsum(hist)[k]; lane l owns k = 2l, 2l+1
    const int2 h   = s_hist2[wave][lane];
    const int incl = wave_iscan_i(h.x + h.y);
    const int inds0 = incl - h.y;
    const int inds1 = incl;

    // weighted reductions (DPP scan; total lands in lane 63)
    const float wrS = wave_iscan_f(w * r);
    const float wgS = wave_iscan_f(w * g);
    const float wbS = wave_iscan_f(w * b);
    const float wmS = wave_iscan_f(w * mid);
    if (lane == 63) {
        float* rgb_out   = out + (size_t)BATCH * NTOT;
        float* depth_out = rgb_out + (size_t)BATCH * 3;
        float* acc_out   = depth_out + BATCH;
        rgb_out[ray * 3 + 0] = wrS;
        rgb_out[ray * 3 + 1] = wgS;
        rgb_out[ray * 3 + 2] = wbS;
        depth_out[ray] = wmS * __builtin_amdgcn_rcpf(wsum + 1e-8f);
        acc_out[ray]   = wsum;
    }

    // Fine samples; merged positions are closed-form (k + below + 1 for fine,
    // lane + t for mids): a permutation of 0..191. Write DIRECTLY to global —
    // 3 scattered dwords per lane inside the ray's 768B segment (all 12 cache
    // lines fully covered by the wave, so no partial-line write penalty).
    float* comb_out = out + (size_t)ray * NTOT;
    #pragma unroll
    for (int i = 0; i < 2; ++i) {
        const int k    = 2 * lane + i;
        const int inds = i ? inds1 : inds0;
        const int below = inds > 0 ? inds - 1 : 0;
        const int above = inds < NS - 1 ? inds : NS - 1;
        const float2 cb2 = s_cm[wave][below];
        const float2 ca2 = s_cm[wave][above];
        float denom = ca2.x - cb2.x;
        if (denom < 1e-5f) denom = 1.0f;
        const float u  = __fmaf_rn(step, (float)k, 0.05f);
        const float tt = (u - cb2.x) * __builtin_amdgcn_rcpf(denom);
        const float fine = __fmaf_rn(tt, ca2.y - cb2.y, cb2.y);
        comb_out[k + below + 1] = fine;
    }
    // mid_j position: j + t_j (j>=1), 0 for j==0
    comb_out[lane ? lane + t : 0] = mid;
}

extern "C" void kernel_launch(void* const* d_in, const int* in_sizes, int n_in,
                              void* d_out, int out_size, void* d_ws, size_t ws_size,
                              hipStream_t stream) {
    const float* near_p  = (const float*)d_in[0];
    const float* far_p   = (const float*)d_in[1];
    const float* density = (const float*)d_in[2];
    const float* rgb     = (const float*)d_in[3];
    float* out = (float*)d_out;

    const int grid = BATCH / WPB;  // 32768 blocks of 256 threads
    pdf_sampler_kernel<<<grid, 256, 0, stream>>>(near_p, far_p, density, rgb, out);
}